// Round 15
// baseline (44.524 us; speedup 1.0000x reference)
//
#include <hip/hip_runtime.h>
#include <hip/hip_fp16.h>

#define BB   128
#define TT   512
#define FF   40
#define WW   10
#define NS   503            // window starts (stride 1): T-W+1
#define NP   780            // F*(F-1)/2
#define SC   84             // steps per block; 503 = 5*84 + 83 -> 6 chunks, ~4 dup steps
#define NCHUNK 6
#define ROWS (SC + WW - 1)  // 93 staged rows
#define NT   512            // threads per block (8 waves); grid 768 = 3 blocks/CU
#define XCOL 100            // xs_t cols: data at 2..94, pad to 100 (100%32=4 -> conflict-free class)
#define SCOL 92             // st_t cols: data at 0..83 (92%32=28 -> same class)
#define EPSC 1e-5f
#define C01  0.31622776601683794f   // sqrt(0.1)

// r14 inner body verbatim (t-major LDS, 4-step fused, 1 b128/output, f16 stats,
// wave-uniform slot1 skip, coalesced stores). Delta: SC 64->84, NCHUNK 8->6 —
// fewer chunks = less per-chunk fixed cost (unrank, initial window, barriers,
// staging overlap), grid 768 = exactly 3 blocks/CU (24 waves/CU).
__global__ __launch_bounds__(NT) void ts_corr_r15(const float* __restrict__ in,
                                                  float* __restrict__ out) {
    const int blk = blockIdx.x;
    const int b   = blk / NCHUNK;
    const int c   = blk - b * NCHUNK;
    const int s0  = (c == NCHUNK - 1) ? (NS - SC) : c * SC;   // 419 tail; overlap rows identical
    const int tid = threadIdx.x;

    __shared__ __align__(16) float   xs_t[FF][XCOL];   // 16000 B
    __shared__ __align__(16) __half2 st_t[FF][SCOL];   // 14720 B  (u*sqrt(0.1), m*u)

    // ---- phase 0: stage transposed (coalesced float4 global reads, 930 quads) ----
    const float4* src4 = (const float4*)(in + ((size_t)b * TT + s0) * FF);
    #pragma unroll
    for (int k = 0; k < 2; ++k) {
        const int q = tid + k * NT;
        if (q < ROWS * FF / 4) {
            const int r  = q / 10;
            const int f0 = (q - r * 10) * 4;
            const float4 v = src4[q];
            xs_t[f0    ][2 + r] = v.x;
            xs_t[f0 + 1][2 + r] = v.y;
            xs_t[f0 + 2][2 + r] = v.z;
            xs_t[f0 + 3][2 + r] = v.w;
        }
    }
    __syncthreads();

    // ---- phase 1 (tid<280): rolling stats, f = tid/7, 12 t's per thread ----
    if (tid < 280) {
        const int f  = tid / 7;
        const int t0 = (tid - f * 7) * 12;
        float sx = 0.f, sq = 0.f;
        #pragma unroll
        for (int w = 0; w < WW; ++w) {
            const float x = xs_t[f][2 + t0 + w];
            sx += x; sq += x * x;
        }
        #pragma unroll
        for (int u = 0; u < 12; ++u) {
            const int t = t0 + u;
            const float m  = sx * 0.1f;
            const float vv = fmaxf(sq * 0.1f - m * m, 0.f);
            const float iu = 1.f / (sqrtf(vv) + EPSC);
            st_t[f][t] = __floats2half2_rn(iu * C01, m * iu);
            if (u < 11) {
                const float xo = xs_t[f][2 + t], xn = xs_t[f][2 + t + WW];
                sx += xn - xo; sq += xn * xn - xo * xo;
            }
        }
    }

    // ---- pair setup + initial window (all threads; xs ready) ----
    int pi[2], pj[2];
    float sxy[2], ph[2][WW];
    #pragma unroll
    for (int k = 0; k < 2; ++k) {
        const int p0 = tid + k * NT;
        const int pp = (p0 < NP) ? p0 : 0;
        int i = (int)((79.0f - sqrtf((float)(6241 - 8 * pp))) * 0.5f);
        while (i > 0 && i * (79 - i) / 2 > pp) --i;
        while ((i + 1) * (79 - (i + 1)) / 2 <= pp) ++i;
        pi[k] = i;
        pj[k] = pp - i * (79 - i) / 2 + i + 1;
        float s = 0.f;
        #pragma unroll
        for (int w2 = 0; w2 < WW; w2 += 2) {
            const float2 a  = *(const float2*)&xs_t[pi[k]][2 + w2];
            const float2 bb = *(const float2*)&xs_t[pj[k]][2 + w2];
            const float q0 = a.x * bb.x, q1 = a.y * bb.y;
            ph[k][w2] = q0; ph[k][w2 + 1] = q1;
            s += q0 + q1;
        }
        sxy[k] = s;
    }
    __syncthreads();   // st ready; no barriers after this

    const bool act1 = (tid < NP - NT);   // slot-1 live (tid<268); wave-uniform skip waves 5..7
    float* dst0 = out + (size_t)(b * NS + s0) * NP + tid;

#define H2F2(U) __half22float2(__builtin_bit_cast(__half2, (U)))

// 4 steps (_tA.._tA+3); U0..U3 literals (static ph indices); DOLAST literal.
#define SLOT4(K, OFF, U0, U1, U2, U3, DOLAST) do {                              \
    const float4 _xi = *(const float4*)&xs_t[pi[K]][2 + _tA + WW];              \
    const float4 _xj = *(const float4*)&xs_t[pj[K]][2 + _tA + WW];              \
    const uint4  _si = *(const uint4*)&st_t[pi[K]][_tA];                        \
    const uint4  _sj = *(const uint4*)&st_t[pj[K]][_tA];                        \
    float2 _a, _b2; float _pn;                                                  \
    _a = H2F2(_si.x); _b2 = H2F2(_sj.x);                                        \
    _d0[OFF] = sxy[K] * _a.x * _b2.x - _a.y * _b2.y;                            \
    _pn = _xi.x * _xj.x; sxy[K] += _pn - ph[K][U0]; ph[K][U0] = _pn;            \
    _a = H2F2(_si.y); _b2 = H2F2(_sj.y);                                        \
    _d1[OFF] = sxy[K] * _a.x * _b2.x - _a.y * _b2.y;                            \
    _pn = _xi.y * _xj.y; sxy[K] += _pn - ph[K][U1]; ph[K][U1] = _pn;            \
    _a = H2F2(_si.z); _b2 = H2F2(_sj.z);                                        \
    _d2[OFF] = sxy[K] * _a.x * _b2.x - _a.y * _b2.y;                            \
    _pn = _xi.z * _xj.z; sxy[K] += _pn - ph[K][U2]; ph[K][U2] = _pn;            \
    _a = H2F2(_si.w); _b2 = H2F2(_sj.w);                                        \
    _d3[OFF] = sxy[K] * _a.x * _b2.x - _a.y * _b2.y;                            \
    if (DOLAST) {                                                               \
        _pn = _xi.w * _xj.w; sxy[K] += _pn - ph[K][U3]; ph[K][U3] = _pn;        \
    }                                                                           \
} while (0)

#define STEP4(U0, U1, U2, U3, TA, DOLAST) do {                                  \
    const int _tA = (TA);                                                       \
    float* _d0 = dst0 + (size_t)_tA * NP;                                       \
    float* _d1 = _d0 + NP;                                                      \
    float* _d2 = _d0 + 2 * NP;                                                  \
    float* _d3 = _d0 + 3 * NP;                                                  \
    SLOT4(0, 0, U0, U1, U2, U3, DOLAST);                                        \
    if (act1) SLOT4(1, NT, U0, U1, U2, U3, DOLAST);                             \
} while (0)

    // ---- phase 2: 84 steps = 4 x 20 (static period-20 history pattern) + 4 ----
    for (int t0 = 0; t0 < 80; t0 += 20) {
        STEP4(0, 1, 2, 3, t0,      true);
        STEP4(4, 5, 6, 7, t0 + 4,  true);
        STEP4(8, 9, 0, 1, t0 + 8,  true);
        STEP4(2, 3, 4, 5, t0 + 12, true);
        STEP4(6, 7, 8, 9, t0 + 16, true);
    }
    STEP4(0, 1, 2, 3, 80, false);   // t=80..83; final .w update dead (reads pad col 95)
#undef STEP4
#undef SLOT4
#undef H2F2
}

extern "C" void kernel_launch(void* const* d_in, const int* in_sizes, int n_in,
                              void* d_out, int out_size, void* d_ws, size_t ws_size,
                              hipStream_t stream) {
    const float* in = (const float*)d_in[0];
    float* out = (float*)d_out;
    ts_corr_r15<<<BB * NCHUNK, NT, 0, stream>>>(in, out);
}